// Round 6
// baseline (229.160 us; speedup 1.0000x reference)
//
#include <hip/hip_runtime.h>
#include <hip/hip_bf16.h>

typedef __bf16 bf16;
typedef __bf16 bf16x8 __attribute__((ext_vector_type(8)));
typedef float f32x4 __attribute__((ext_vector_type(4)));

#define BB 64
#define EMB 256
#define UNITS 512
#define POI 5000
#define KCAT 1280
#define SCLD 5024   // sc row stride (5000 padded to x32)
#define L2E 1.4426950408889634f

__device__ __forceinline__ float rcp_(float x){ return __builtin_amdgcn_rcpf(x); }
__device__ __forceinline__ float exp2_(float x){ return __builtin_amdgcn_exp2f(x); }

// ---- one 16x16x(K) MFMA C-tile from fp32 sources, on-the-fly bf16 cvt.
// A fp32 row-major [*, lda]: lane -> A[mr][q*8+j]. B fp32 row-major [K, ldb]: lane -> B[q*8+j][nc].
// C/D: col=lane&15, row=q*4+reg (validated by R3-R5 passes).
__device__ __forceinline__ f32x4 mm16f(const float* __restrict__ A, const float* __restrict__ B,
                                       int lda, int ldb, int K, int mr, int nc, int lane){
  int q = lane >> 4;
  f32x4 acc = {0.f,0.f,0.f,0.f};
  const float* ap = A + (size_t)mr*lda + q*8;
  const float* bp = B + (size_t)(q*8)*ldb + nc;
#pragma unroll 2
  for(int k0 = 0; k0 < K; k0 += 32){
    f32x4 a0 = *(const f32x4*)ap;
    f32x4 a1 = *(const f32x4*)(ap+4);
    bf16x8 a, b;
#pragma unroll
    for(int j=0;j<4;j++){ a[j] = (bf16)a0[j]; a[4+j] = (bf16)a1[j]; }
#pragma unroll
    for(int j=0;j<8;j++) b[j] = (bf16)bp[(size_t)j*ldb];
    acc = __builtin_amdgcn_mfma_f32_16x16x32_bf16(a, b, acc, 0, 0, 0);
    ap += 32; bp += (size_t)32*ldb;
  }
  return acc;
}

// ---- merged GRU GEMMs, split-K x2, x1 gather inlined. grid (96, 2, 2).
// y: 0 = x1@gruK (x1 = [emb[x[m]] | query[m]]), 1 = h0@gruR. z: k-half (256 each).
__global__ __launch_bounds__(256) void k_gru(const int* __restrict__ x,
    const float* __restrict__ query, const float* __restrict__ emb, const float* __restrict__ h0,
    const float* __restrict__ gruK, const float* __restrict__ gruR,
    float* __restrict__ xmP, float* __restrict__ hmP){
  int lane = threadIdx.x & 63, w = threadIdx.x >> 6;
  int col = blockIdx.x*16 + (lane & 15);
  int m = w*16 + (lane & 15);
  int z = blockIdx.z;
  const float* A; const float* B; int lda, mr;
  if(blockIdx.y == 0){
    B = gruK + (size_t)(z*256)*1536;
    if(z == 0){ A = emb;   mr = x[m]; lda = EMB; }   // emb[x[m]][0:256]
    else      { A = query; mr = m;    lda = 256; }   // query[m][0:256]
  } else {
    B = gruR + (size_t)(z*256)*1536;
    A = h0 + z*256; mr = m; lda = UNITS;
  }
  f32x4 acc = mm16f(A, B, lda, 1536, 256, mr, col, lane);
  float* C = (blockIdx.y ? hmP : xmP) + (size_t)z*BB*1536;
  int rb = w*16 + (lane >> 4)*4;
#pragma unroll
  for(int r=0;r<4;r++) C[(size_t)(rb+r)*1536 + col] = acc[r];
}

// ---- GRU gates (keras reset_after=True, z/r/h); sums 2 k-split slabs; copies cat_dec into outc
__global__ void k_gates(const float* __restrict__ xmP, const float* __restrict__ hmP,
                        const float* __restrict__ bias, const float* __restrict__ h0,
                        const float* __restrict__ catd,
                        float* __restrict__ hn, float* __restrict__ outc, float* __restrict__ dout){
  int b = blockIdx.x, u = threadIdx.x;  // 512 thr
  const float* x0 = xmP + b*1536; const float* x1s = xmP + (size_t)BB*1536 + b*1536;
  const float* h0s = hmP + b*1536; const float* h1s = hmP + (size_t)BB*1536 + b*1536;
  float xz = x0[u]      + x1s[u]      + bias[u];
  float xg = x0[512+u]  + x1s[512+u]  + bias[512+u];
  float xh = x0[1024+u] + x1s[1024+u] + bias[1024+u];
  float hz = h0s[u]      + h1s[u]      + bias[1536+u];
  float hg = h0s[512+u]  + h1s[512+u]  + bias[2048+u];
  float hh = h0s[1024+u] + h1s[1024+u] + bias[2560+u];
  float z = rcp_(1.f + exp2_(-L2E*(xz+hz)));
  float r = rcp_(1.f + exp2_(-L2E*(xg+hg)));
  float ca = xh + r*hh;
  ca = fminf(fmaxf(ca, -15.f), 15.f);
  float e = exp2_(2.f*L2E*ca);
  float hc = (e - 1.f)*rcp_(e + 1.f);
  float h = h0[b*512+u];
  float v = z*h + (1.f - z)*hc;
  hn[b*512+u] = v;
  outc[b*KCAT + 256 + u] = v;
  outc[b*KCAT + 768 + u] = catd[(size_t)b*512 + u];
  dout[(size_t)POI*BB + (size_t)b*512 + u] = v;                       // state
  dout[(size_t)POI*BB + (size_t)BB*512 + (size_t)b*512 + u] = v;      // output_
}

// ---- Eq = exp2(clamp(2*log2e*(hn@W2 + b2), +-28)) : [64,512]. grid 32.
__global__ __launch_bounds__(256) void k_qproj(const float* __restrict__ hn, const float* __restrict__ W2,
                        const float* __restrict__ W2b, float* __restrict__ Eq){
  int lane = threadIdx.x & 63, w = threadIdx.x >> 6;
  int col = blockIdx.x*16 + (lane & 15);
  f32x4 acc = mm16f(hn, W2, UNITS, UNITS, UNITS, w*16 + (lane & 15), col, lane);
  float bn = W2b[col];
  int rb = w*16 + (lane >> 4)*4;
#pragma unroll
  for(int r=0;r<4;r++){
    float v = (acc[r] + bn)*(2.f*L2E);
    Eq[(rb+r)*UNITS + col] = exp2_(fminf(fmaxf(v, -28.f), 28.f));
  }
}

// ---- fused vproj+score, grid (313, 8): 16 poi rows x 64-u eighth per block.
// stage1 MFMA -> Ev eighth in LDS; stage2: 2-way-combined rcp sum; atomicAdd partial into sc.
// tanh identity ( sum w*tanh = SW - 2*sum w/(EvEq+1) ) absorbed into softmax exp (SW cancels).
__global__ __launch_bounds__(256) void k_vscore(const float* __restrict__ emb, const float* __restrict__ W1,
    const float* __restrict__ W1b, const float* __restrict__ Eq,
    const float* __restrict__ Vw, float* __restrict__ sc){
  __shared__ float evs[16][68];
  __shared__ float Qs[64][68];
  __shared__ float vws[64];
  int t = threadIdx.x, lane = t & 63, w = t >> 6;
  int p0 = blockIdx.x*16, uh = blockIdx.y*64;
  int mr = p0 + (lane & 15); if(mr > POI-1) mr = POI-1;   // tail clamp
  {
    int ncl = w*16 + (lane & 15);                          // local col 0..63 (1 tile/wave)
    f32x4 acc = mm16f(emb, W1, EMB, UNITS, EMB, mr, uh + ncl, lane);
    float bn = W1b[uh + ncl];
    int rb = (lane >> 4)*4;
#pragma unroll
    for(int r=0;r<4;r++){
      float v = (acc[r] + bn)*(2.f*L2E);
      evs[rb+r][ncl] = exp2_(fminf(fmaxf(v, -28.f), 28.f));
    }
  }
  for(int i=t;i<1024;i+=256){ int b=i>>4, u4=i&15; *(f32x4*)&Qs[b][u4*4] = *(const f32x4*)&Eq[b*UNITS + uh + u4*4]; }
  if(t < 64) vws[t] = Vw[uh + t];
  __syncthreads();                     // single barrier: evs+Qs+vws ready
  int tp = t & 7, tb = t >> 3;
  float s00=0.f, s01=0.f, s10=0.f, s11=0.f;
#pragma unroll
  for(int u4=0;u4<16;u4++){
    f32x4 e0 = *(f32x4*)&evs[2*tp][u4*4];
    f32x4 e1 = *(f32x4*)&evs[2*tp+1][u4*4];
    f32x4 q0 = *(f32x4*)&Qs[2*tb][u4*4];
    f32x4 q1 = *(f32x4*)&Qs[2*tb+1][u4*4];
    f32x4 w4 = *(f32x4*)&vws[u4*4];
#pragma unroll
    for(int h=0;h<2;h++){              // u-pairs (0,1),(2,3): 1 rcp per 2 elements
      int i0 = 2*h, i1 = 2*h+1;
      float w0 = w4[i0], w1 = w4[i1];
      float da, db;
      da = __builtin_fmaf(e0[i0], q0[i0], 1.f); db = __builtin_fmaf(e0[i1], q0[i1], 1.f);
      s00 = __builtin_fmaf(__builtin_fmaf(w0, db, w1*da), rcp_(da*db), s00);
      da = __builtin_fmaf(e0[i0], q1[i0], 1.f); db = __builtin_fmaf(e0[i1], q1[i1], 1.f);
      s01 = __builtin_fmaf(__builtin_fmaf(w0, db, w1*da), rcp_(da*db), s01);
      da = __builtin_fmaf(e1[i0], q0[i0], 1.f); db = __builtin_fmaf(e1[i1], q0[i1], 1.f);
      s10 = __builtin_fmaf(__builtin_fmaf(w0, db, w1*da), rcp_(da*db), s10);
      da = __builtin_fmaf(e1[i0], q1[i0], 1.f); db = __builtin_fmaf(e1[i1], q1[i1], 1.f);
      s11 = __builtin_fmaf(__builtin_fmaf(w0, db, w1*da), rcp_(da*db), s11);
    }
  }
  int pA = p0 + 2*tp, bA = 2*tb;
  if(pA < POI){
    atomicAdd(&sc[(size_t)bA*SCLD + pA],     s00);
    atomicAdd(&sc[(size_t)(bA+1)*SCLD + pA], s01);
  }
  if(pA+1 < POI){
    atomicAdd(&sc[(size_t)bA*SCLD + pA+1],     s10);
    atomicAdd(&sc[(size_t)(bA+1)*SCLD + pA+1], s11);
  }
}

// ---- per-b: weight = exp2(-2*L2E*a) (SW cancels, tanh-bounded => no max-sub needed);
// normalize in place; zero pad; zero outc ctx region. grid 64, 1024 thr.
__global__ __launch_bounds__(1024) void k_softmax(float* __restrict__ sc, float* __restrict__ outc){
  __shared__ float red[1024];
  int b = blockIdx.x, t = threadIdx.x;
  if(t < 256) outc[b*KCAT + t] = 0.f;        // zero ctx accumulator region
  float* sA = sc + (size_t)b*SCLD;
  float sum = 0.f;
  for(int p=t;p<POI;p+=1024){
    float wv = exp2_(-2.f*L2E*sA[p]);
    sA[p] = wv;
    sum += wv;
  }
  red[t] = sum; __syncthreads();
  for(int o=512;o>0;o>>=1){ if(t<o) red[t]+=red[t+o]; __syncthreads(); }
  float iv = rcp_(red[0]);
  for(int p=t;p<POI;p+=1024) sA[p] *= iv;    // normalized attention weights
  if(t < SCLD-POI) sA[POI + t] = 0.f;        // zero k-pad for ctx GEMM
}

// ---- context = wb[64,5024] @ emb[5000,256] (split-K x13, atomic) -> outc[:,0:256]
__global__ __launch_bounds__(256) void k_ctx(const float* __restrict__ wb, const float* __restrict__ emb,
                                             float* __restrict__ outc){
  int lane = threadIdx.x & 63, w = threadIdx.x >> 6;
  int n = blockIdx.x*16 + (lane & 15);       // n < 256
  int ky = blockIdx.y;                        // 13 splits of 384
  int kbeg = ky*384;
  int mr = w*16 + (lane & 15);
  f32x4 acc = mm16f(wb + kbeg, emb + (size_t)kbeg*EMB, SCLD, EMB, 384, mr, n, lane);
  if(ky == 12){                               // tail [4992,5024): wb pad=0, emb row clamped
    int q = lane >> 4;
    const float* ap = wb + (size_t)mr*SCLD + 4992 + q*8;
    bf16x8 a, bfr;
#pragma unroll
    for(int j=0;j<8;j++) a[j] = (bf16)ap[j];
#pragma unroll
    for(int j=0;j<8;j++){
      int k = 4992 + q*8 + j; int kc = k < POI ? k : POI-1;
      bfr[j] = (bf16)emb[(size_t)kc*EMB + n];
    }
    acc = __builtin_amdgcn_mfma_f32_16x16x32_bf16(a, bfr, acc, 0, 0, 0);
  }
  int rb = w*16 + (lane >> 4)*4;
#pragma unroll
  for(int r=0;r<4;r++) atomicAdd(&outc[(size_t)(rb+r)*KCAT + n], acc[r]);
}

// ---- logits: split-K x4, atomicAdd into zeroed d_out; bias folded into split 0. grid (313,4).
__global__ __launch_bounds__(256) void k_logits(const float* __restrict__ A, const float* __restrict__ Bw,
                        const float* __restrict__ fcb, float* __restrict__ out){
  int lane = threadIdx.x & 63, w = threadIdx.x >> 6;
  int n = blockIdx.x*16 + (lane & 15);
  int nc = n < POI ? n : POI-1;
  int ky = blockIdx.y, kbeg = ky*320;         // 4 x 320 = 1280
  f32x4 acc = mm16f(A + kbeg, Bw + (size_t)kbeg*POI, KCAT, POI, 320,
                    w*16 + (lane & 15), nc, lane);
  int rb = w*16 + (lane >> 4)*4;
  if(n < POI){
    float bn = (ky == 0) ? fcb[n] : 0.f;
#pragma unroll
    for(int r=0;r<4;r++) atomicAdd(&out[(size_t)(rb+r)*POI + n], acc[r] + bn);
  }
}

extern "C" void kernel_launch(void* const* d_in, const int* in_sizes, int n_in,
                              void* d_out, int out_size, void* d_ws, size_t ws_size,
                              hipStream_t stream){
  const int*   x     = (const int*)d_in[0];
  const float* query = (const float*)d_in[1];
  const float* emb   = (const float*)d_in[2];
  // d_in[3] A_hat unused by reference
  const float* h0    = (const float*)d_in[4];
  const float* catd  = (const float*)d_in[5];
  const float* gruK  = (const float*)d_in[6];
  const float* gruR  = (const float*)d_in[7];
  const float* gruB  = (const float*)d_in[8];
  const float* W1    = (const float*)d_in[9];
  const float* W1b   = (const float*)d_in[10];
  const float* W2    = (const float*)d_in[11];
  const float* W2b   = (const float*)d_in[12];
  const float* Vw    = (const float*)d_in[13];
  // d_in[14] V_b: softmax-invariant, dropped
  const float* fcw   = (const float*)d_in[15];
  const float* fcb   = (const float*)d_in[16];
  float* out = (float*)d_out;

  char* ws = (char*)d_ws;
  size_t off = 0;
  auto alloc = [&](size_t bytes)->void*{ void* p = ws + off; off += (bytes + 255) & ~(size_t)255; return p; };
  float* outc = (float*)alloc((size_t)BB*KCAT*4);
  float* xmP  = (float*)alloc((size_t)2*BB*1536*4);
  float* hmP  = (float*)alloc((size_t)2*BB*1536*4);
  float* hn   = (float*)alloc((size_t)BB*512*4);
  float* Eq   = (float*)alloc((size_t)BB*512*4);
  float* sc   = (float*)alloc((size_t)BB*SCLD*4);
  // total ~4.1 MB

  hipMemsetAsync(out, 0, (size_t)BB*POI*4, stream);   // logits atomic accumulator
  hipMemsetAsync(sc, 0, (size_t)BB*SCLD*4, stream);   // score atomic accumulator
  k_gru    <<<dim3(96,2,2), 256, 0, stream>>>(x, query, emb, h0, gruK, gruR, xmP, hmP);
  k_gates  <<<BB, 512, 0, stream>>>(xmP, hmP, gruB, h0, catd, hn, outc, out);
  k_qproj  <<<32, 256, 0, stream>>>(hn, W2, W2b, Eq);
  k_vscore <<<dim3(313,8), 256, 0, stream>>>(emb, W1, W1b, Eq, Vw, sc);
  k_softmax<<<BB, 1024, 0, stream>>>(sc, outc);
  k_ctx    <<<dim3(16,13), 256, 0, stream>>>(sc, emb, outc);
  k_logits <<<dim3(313,4), 256, 0, stream>>>(outc, fcw, fcb, out);
}